// Round 17
// baseline (268.322 us; speedup 1.0000x reference)
//
#include <hip/hip_runtime.h>
#include <hip/hip_bf16.h>

typedef float f32x4  __attribute__((ext_vector_type(4)));
typedef float f32x16 __attribute__((ext_vector_type(16)));
typedef short short8 __attribute__((ext_vector_type(8)));

#define NT    325
#define DKK   32
#define NSL   384                 // B*H*T
#define SLICE (NT*DKK)            // 10400
#define TOTE  (NSL*SLICE)         // per-output-tensor elements
#define NKT   21                  // ceil(325/16) (fat kernel)
#define NQT32 11                  // ceil(325/32) (slim kernel)
#define PADV  352                 // 11*32, padded m for PV
#define VGRAN (32 * (PADV/8))     // 1408 16B-granules in Vt
// 1/sqrt(32) * log2(e)
#define SCALE2 0.25506372f

// XOR swizzle on short-index (byte bits 4..6).
__device__ __forceinline__ int swz(int sidx, int row) { return sidx ^ ((row & 7) << 3); }

__device__ __forceinline__ unsigned cvtpk(float lo, float hi) {
    unsigned r;
    asm("v_cvt_pk_bf16_f32 %0, %1, %2" : "=v"(r) : "v"(lo), "v"(hi));
    return r;
}
__device__ __forceinline__ unsigned pk2_split(float x, float y, unsigned& lopk) {
    const unsigned hi = cvtpk(x, y);
    const float hx = __builtin_bit_cast(float, hi << 16);
    const float hy = __builtin_bit_cast(float, hi & 0xffff0000u);
    lopk = cvtpk(x - hx, y - hy);
    return hi;
}
__device__ __forceinline__ void swap32(unsigned& a, unsigned& b) {
    asm("v_permlane32_swap_b32 %0, %1" : "+v"(a), "+v"(b));
}
__device__ __forceinline__ void swap16(unsigned& a, unsigned& b) {
    asm("v_permlane16_swap_b32 %0, %1" : "+v"(a), "+v"(b));
}
// 16x16 P repack (fat kernel; verified r9/r12).
__device__ __forceinline__ short8 repack(const f32x4& a0, const f32x4& a1, bool hasB) {
    unsigned u = cvtpk(a0[0], a0[1]);
    unsigned v = cvtpk(a0[2], a0[3]);
    unsigned s = hasB ? cvtpk(a1[0], a1[1]) : 0u;
    unsigned t = hasB ? cvtpk(a1[2], a1[3]) : 0u;
    swap32(u, s); swap16(u, s);
    swap32(v, t); swap16(v, t);
    uint4 w; w.x = u; w.y = v; w.z = s; w.w = t;
    return __builtin_bit_cast(short8, w);
}

// ============================ SLIM kernel (32x32 MFMA) ======================
// vars {0,2,3}. One wave = one 32q tile per pass; score D = mfma32(K,Q):
// lane holds S[m_local set][q=lane&31] (all m of a row in ONE lane pair).
// PV: A-frag via 8 cvtpk + 4 permlane32_swap; B = Vt rows (d-major).
// Kb sized 352 rows (chunk 10 reads m..351; stale rows masked pre-exp2).
// LDS = 22528*2 = 45056 -> 3 blocks/CU.
__global__ __launch_bounds__(512, 3)
void attn_slim(const float* __restrict__ Qf, const float* __restrict__ Kf,
               const float* __restrict__ Vf, const float* __restrict__ Qs,
               const float* __restrict__ Ks, const float* __restrict__ Vs,
               float* __restrict__ out)
{
    __shared__ __align__(16) unsigned short Kb[PADV * DKK];  // [m][d] bf16 (swizzled)
    __shared__ __align__(16) unsigned short Vt[DKK * PADV];  // [d][m] bf16 (swizzled)

    const int tid = threadIdx.x;
    const int bid = blockIdx.x;
    const int bt  = bid / 3;
    const int vr  = bid - 3 * bt;
    const int vi  = (vr + bt) % 3;
    const int var = (vi == 0) ? 0 : (vi == 1) ? 2 : 3;
    const size_t base = (size_t)bt * SLICE;

    const float *qp, *kp, *vp;
    if      (var == 0) { qp = Qf; kp = Kf; vp = Vf; }
    else if (var == 2) { qp = Ks; kp = Qf; vp = Vs; }
    else               { qp = Qs; kp = Ks; vp = Vs; }
    float* op = out + (size_t)var * TOTE + base;

    // ---- stage K -> Kb (bf16, swizzled); zero rows 325..351 ----
    for (int i8 = tid; i8 < (PADV * DKK) / 8; i8 += 512) {
        const int idx = i8 * 8;
        const int m   = idx >> 5;
        uint4 pkv;
        if (m < NT) {
            const float* s = kp + base + idx;
            const float4 a = *(const float4*)s;
            const float4 b = *(const float4*)(s + 4);
            pkv.x = cvtpk(a.x, a.y); pkv.y = cvtpk(a.z, a.w);
            pkv.z = cvtpk(b.x, b.y); pkv.w = cvtpk(b.z, b.w);
        } else {
            pkv.x = pkv.y = pkv.z = pkv.w = 0u;
        }
        *(uint4*)&Kb[swz(idx, m)] = pkv;
    }

    // ---- stage V -> Vt (bf16, transposed, zero-padded, swizzled, coalesced) ----
    for (int gi = tid; gi < VGRAN; gi += 512) {
        const int dd = gi & 31;
        const int m8 = gi >> 5;           // 0..43
        const int mb = m8 * 8;
        float v[8];
        #pragma unroll
        for (int i = 0; i < 8; ++i) {
            const int m = mb + i;
            v[i] = (m < NT) ? vp[base + (size_t)m * DKK + dd] : 0.0f;
        }
        uint4 pkv;
        pkv.x = cvtpk(v[0], v[1]); pkv.y = cvtpk(v[2], v[3]);
        pkv.z = cvtpk(v[4], v[5]); pkv.w = cvtpk(v[6], v[7]);
        *(uint4*)&Vt[swz(dd * PADV + mb, dd)] = pkv;
    }
    __syncthreads();

    const int lane = tid & 63;
    const int wv   = tid >> 6;                // 0..7
    const int l31  = lane & 31;
    const int h    = lane >> 5;               // 0,1
    const int d0   = h * 8;
    const int swz8 = (lane & 7) << 3;         // row&7 == lane&7 for all frag reads
    const f32x16 zero16 = {0,0,0,0,0,0,0,0,0,0,0,0,0,0,0,0};

    for (int qt = wv; qt < NQT32; qt += 8) {
        // Q B-frags: lane covers q = qt*32+l31, d = d0..d0+7 and 16+d0..16+d0+7
        int qr = qt * 32 + l31; if (qr > NT - 1) qr = NT - 1;
        const float* qsrc = qp + base + (size_t)qr * DKK;
        const float4 qA = *(const float4*)(qsrc + d0);
        const float4 qB = *(const float4*)(qsrc + d0 + 4);
        const float4 qC = *(const float4*)(qsrc + 16 + d0);
        const float4 qD = *(const float4*)(qsrc + 16 + d0 + 4);
        uint4 w1, w2;
        w1.x = cvtpk(qA.x * SCALE2, qA.y * SCALE2);
        w1.y = cvtpk(qA.z * SCALE2, qA.w * SCALE2);
        w1.z = cvtpk(qB.x * SCALE2, qB.y * SCALE2);
        w1.w = cvtpk(qB.z * SCALE2, qB.w * SCALE2);
        w2.x = cvtpk(qC.x * SCALE2, qC.y * SCALE2);
        w2.y = cvtpk(qC.z * SCALE2, qC.w * SCALE2);
        w2.z = cvtpk(qD.x * SCALE2, qD.y * SCALE2);
        w2.w = cvtpk(qD.z * SCALE2, qD.w * SCALE2);
        const short8 q1 = __builtin_bit_cast(short8, w1);
        const short8 q2 = __builtin_bit_cast(short8, w2);

        f32x16 o = zero16;
        float ts0 = 0.f, ts1 = 0.f, ts2 = 0.f, ts3 = 0.f;

        #pragma unroll
        for (int ks = 0; ks < NQT32; ++ks) {
            const int mrow = ks * 32 + l31;
            const int ki1 = (mrow * DKK + d0) ^ swz8;
            const int ki2 = (mrow * DKK + 16 + d0) ^ swz8;
            const short8 k1 = *(const short8*)&Kb[ki1];
            const short8 k2 = *(const short8*)&Kb[ki2];

            __builtin_amdgcn_s_setprio(1);
            f32x16 a = __builtin_amdgcn_mfma_f32_32x32x16_bf16(k1, q1, zero16, 0, 0, 0);
            a = __builtin_amdgcn_mfma_f32_32x32x16_bf16(k2, q2, a, 0, 0, 0);
            __builtin_amdgcn_s_setprio(0);

            if (ks == 10) {   // mask m >= 325: m_local = (r&3)+8*(r>>2)+4h > 4
                #pragma unroll
                for (int r = 0; r < 16; ++r) {
                    const int ml = (r & 3) + 8 * (r >> 2) + 4 * h;
                    a[r] = (ml > 4) ? -1e30f : a[r];
                }
            }

            // |s| small in log2 domain: no max subtraction. All 16 regs same q.
            #pragma unroll
            for (int r = 0; r < 16; ++r) a[r] = exp2f(a[r]);
            ts0 += (a[0] + a[1]) + (a[2] + a[3]);
            ts1 += (a[4] + a[5]) + (a[6] + a[7]);
            ts2 += (a[8] + a[9]) + (a[10] + a[11]);
            ts3 += (a[12] + a[13]) + (a[14] + a[15]);

            // PV A-frags: regs 0..7 -> k=m_local 0..15; regs 8..15 -> 16..31.
            unsigned u1 = cvtpk(a[0],  a[1]),  v1w = cvtpk(a[2],  a[3]);
            unsigned s1 = cvtpk(a[4],  a[5]),  t1  = cvtpk(a[6],  a[7]);
            swap32(u1, s1); swap32(v1w, t1);
            uint4 wa; wa.x = u1; wa.y = v1w; wa.z = s1; wa.w = t1;
            const short8 af1 = __builtin_bit_cast(short8, wa);
            unsigned u2 = cvtpk(a[8],  a[9]),  v2w = cvtpk(a[10], a[11]);
            unsigned s2 = cvtpk(a[12], a[13]), t2  = cvtpk(a[14], a[15]);
            swap32(u2, s2); swap32(v2w, t2);
            uint4 wb; wb.x = u2; wb.y = v2w; wb.z = s2; wb.w = t2;
            const short8 af2 = __builtin_bit_cast(short8, wb);

            // V B-frags: lane needs V[m = ks*32 + half*16 + h*8 + j][d=l31]
            const int vi1 = (l31 * PADV + ks * 32 + d0) ^ swz8;
            const int vi2 = (l31 * PADV + ks * 32 + 16 + d0) ^ swz8;
            const short8 vf1 = *(const short8*)&Vt[vi1];
            const short8 vf2 = *(const short8*)&Vt[vi2];

            __builtin_amdgcn_s_setprio(1);
            o = __builtin_amdgcn_mfma_f32_32x32x16_bf16(af1, vf1, o, 0, 0, 0);
            o = __builtin_amdgcn_mfma_f32_32x32x16_bf16(af2, vf2, o, 0, 0, 0);
            __builtin_amdgcn_s_setprio(0);
        }

        float ts = (ts0 + ts1) + (ts2 + ts3);
        ts += __shfl_xor(ts, 32);             // lane pair (l, l+32) share q = l31
        const float inv = 1.0f / ts;

        #pragma unroll
        for (int r = 0; r < 16; ++r) {
            const int ql  = (r & 3) + 8 * (r >> 2) + 4 * h;   // q within tile
            const int row = qt * 32 + ql;
            const float iv = __shfl(inv, ql);                  // lane ql holds full sum
            if (row < NT) op[(size_t)row * DKK + l31] = o[r] * iv;
        }
    }
}

// ============================= FAT kernel (r16, unchanged) ==================
__global__ __launch_bounds__(512, 2)
void attn_fat(const float* __restrict__ Kf, const float* __restrict__ Vf,
              const float* __restrict__ Qs,
              const float* __restrict__ Kj, const float* __restrict__ Vfp,
              float* __restrict__ out)
{
    __shared__ __align__(16) unsigned short Kb[336 * DKK];   // bf16 hi (swizzled)
    __shared__ __align__(16) unsigned short Kl[336 * DKK];   // bf16 lo (swizzled)
    __shared__ __align__(16) unsigned short Vt[DKK * PADV];  // [d][m] bf16 (swizzled)

    const int tid = threadIdx.x;
    const int bt  = blockIdx.x;
    const size_t base = (size_t)bt * SLICE;

    const float* qp = Kf;
    const float* kp = Qs;
    const float* vp = Vf;
    float* op = out + (size_t)1 * TOTE + base;

    for (int i8 = tid; i8 < SLICE / 8; i8 += 512) {
        const int idx = i8 * 8;
        const int m   = idx >> 5;
        const int sidx = swz(idx, m);
        const float* s = kp + base + idx;
        float4 a = *(const float4*)s;
        float4 b = *(const float4*)(s + 4);
        const float kj = Kj[m];
        const float rv = 1.0f / (Vfp[m] + 1e-5f);
        a.x = kj * (a.x - a.x * a.x * rv);
        a.y = kj * (a.y - a.y * a.y * rv);
        a.z = kj * (a.z - a.z * a.z * rv);
        a.w = kj * (a.w - a.w * a.w * rv);
        b.x = kj * (b.x - b.x * b.x * rv);
        b.y = kj * (b.y - b.y * b.y * rv);
        b.z = kj * (b.z - b.z * b.z * rv);
        b.w = kj * (b.w - b.w * b.w * rv);
        uint4 hw, lw;
        hw.x = pk2_split(a.x, a.y, lw.x);
        hw.y = pk2_split(a.z, a.w, lw.y);
        hw.z = pk2_split(b.x, b.y, lw.z);
        hw.w = pk2_split(b.z, b.w, lw.w);
        *(uint4*)&Kb[sidx] = hw;
        *(uint4*)&Kl[sidx] = lw;
    }

    for (int gi = tid; gi < VGRAN; gi += 512) {
        const int dd = gi & 31;
        const int m8 = gi >> 5;
        const int mb = m8 * 8;
        float v[8];
        #pragma unroll
        for (int i = 0; i < 8; ++i) {
            const int m = mb + i;
            v[i] = (m < NT) ? vp[base + (size_t)m * DKK + dd] : 0.0f;
        }
        uint4 pkv;
        pkv.x = cvtpk(v[0], v[1]); pkv.y = cvtpk(v[2], v[3]);
        pkv.z = cvtpk(v[4], v[5]); pkv.w = cvtpk(v[6], v[7]);
        *(uint4*)&Vt[swz(dd * PADV + mb, dd)] = pkv;
    }
    __syncthreads();

    const int lane = tid & 63;
    const int wv   = tid >> 6;
    const int c    = lane & 15;
    const int g    = lane >> 4;
    const int kswz = (c & 7) << 3;
    const f32x4 zero = {0.f, 0.f, 0.f, 0.f};

    int qt = wv;
    float4 qa, qb;
    {
        int qr = qt * 16 + c; if (qr > NT - 1) qr = NT - 1;
        const float* s = qp + base + (size_t)qr * DKK + g * 8;
        qa = *(const float4*)s; qb = *(const float4*)(s + 4);
    }

    for (; qt < NKT; qt += 8) {
        float4 na, nb;
        const bool more = (qt + 8) < NKT;
        if (more) {
            int qr = (qt + 8) * 16 + c; if (qr > NT - 1) qr = NT - 1;
            const float* s = qp + base + (size_t)qr * DKK + g * 8;
            na = *(const float4*)s; nb = *(const float4*)(s + 4);
        }

        uint4 qwh, qwl;
        qwh.x = pk2_split(qa.x * SCALE2, qa.y * SCALE2, qwl.x);
        qwh.y = pk2_split(qa.z * SCALE2, qa.w * SCALE2, qwl.y);
        qwh.z = pk2_split(qb.x * SCALE2, qb.y * SCALE2, qwl.z);
        qwh.w = pk2_split(qb.z * SCALE2, qb.w * SCALE2, qwl.w);
        const short8 qh = __builtin_bit_cast(short8, qwh);
        const short8 ql = __builtin_bit_cast(short8, qwl);

        f32x4 o0a = zero, o1a = zero, o0b = zero, o1b = zero;
        float ts0 = 0.f, ts1 = 0.f, ts2 = 0.f, ts3 = 0.f;
        float mrow = -1e30f;

        #pragma unroll
        for (int ks = 0; ks < 11; ++ks) {
            const int fi0 = (((2 * ks) * 16 + c) * DKK + g * 8) ^ kswz;
            const int fi1 = fi0 + 16 * DKK;
            const bool hasB1 = (ks < 10);
            f32x4 a0, a1;

            __builtin_amdgcn_s_setprio(1);
            {
                const short8 kh = *(const short8*)&Kb[fi0];
                const short8 kl = *(const short8*)&Kl[fi0];
                f32x4 t = __builtin_amdgcn_mfma_f32_16x16x32_bf16(kh, ql, zero, 0, 0, 0);
                t = __builtin_amdgcn_mfma_f32_16x16x32_bf16(kl, qh, t, 0, 0, 0);
                a0 = __builtin_amdgcn_mfma_f32_16x16x32_bf16(kh, qh, t, 0, 0, 0);
            }
            if (hasB1) {
                const short8 kh = *(const short8*)&Kb[fi1];
                const short8 kl = *(const short8*)&Kl[fi1];
                f32x4 t = __builtin_amdgcn_mfma_f32_16x16x32_bf16(kh, ql, zero, 0, 0, 0);
                t = __builtin_amdgcn_mfma_f32_16x16x32_bf16(kl, qh, t, 0, 0, 0);
                a1 = __builtin_amdgcn_mfma_f32_16x16x32_bf16(kh, qh, t, 0, 0, 0);
            }
            __builtin_amdgcn_s_setprio(0);

            if (ks == 10) {
                #pragma unroll
                for (int r = 0; r < 4; ++r)
                    a0[r] = (4 * g + r > 4) ? -1e30f : a0[r];
            }

            float pm = fmaxf(fmaxf(a0[0], a0[1]), fmaxf(a0[2], a0[3]));
            if (hasB1)
                pm = fmaxf(pm, fmaxf(fmaxf(a1[0], a1[1]), fmaxf(a1[2], a1[3])));
            pm = fmaxf(pm, __shfl_xor(pm, 16));
            pm = fmaxf(pm, __shfl_xor(pm, 32));
            if (__any(pm > mrow)) {
                const float mn = fmaxf(mrow, pm);
                const float f = exp2f(mrow - mn);
                mrow = mn;
                ts0 *= f; ts1 *= f; ts2 *= f; ts3 *= f;
                #pragma unroll
                for (int r = 0; r < 4; ++r) {
                    const float fr = __shfl(f, 4 * g + r);
                    o0a[r] *= fr; o1a[r] *= fr;
                    o0b[r] *= fr; o1b[r] *= fr;
                }
            }
            a0[0] = exp2f(a0[0] - mrow); a0[1] = exp2f(a0[1] - mrow);
            a0[2] = exp2f(a0[2] - mrow); a0[3] = exp2f(a0[3] - mrow);
            ts0 += a0[0]; ts1 += a0[1]; ts2 += a0[2]; ts3 += a0[3];
            if (hasB1) {
                a1[0] = exp2f(a1[0] - mrow); a1[1] = exp2f(a1[1] - mrow);
                a1[2] = exp2f(a1[2] - mrow); a1[3] = exp2f(a1[3] - mrow);
                ts0 += a1[0]; ts1 += a1[1]; ts2 += a1[2]; ts3 += a1[3];
            }

            const short8 af = repack(a0, hasB1 ? a1 : a0, hasB1);
            const short8 v0 = *(const short8*)&Vt[( c        * PADV + ks * 32 + g * 8) ^ kswz];
            const short8 v1 = *(const short8*)&Vt[((c + 16)  * PADV + ks * 32 + g * 8) ^ kswz];
            __builtin_amdgcn_s_setprio(1);
            if (ks & 1) {
                o0b = __builtin_amdgcn_mfma_f32_16x16x32_bf16(af, v0, o0b, 0, 0, 0);
                o1b = __builtin_amdgcn_mfma_f32_16x16x32_bf16(af, v1, o1b, 0, 0, 0);
            } else {
                o0a = __builtin_amdgcn_mfma_f32_16x16x32_bf16(af, v0, o0a, 0, 0, 0);
                o1a = __builtin_amdgcn_mfma_f32_16x16x32_bf16(af, v1, o1a, 0, 0, 0);
            }
            __builtin_amdgcn_s_setprio(0);
        }

        float ts = (ts0 + ts1) + (ts2 + ts3);
        ts += __shfl_xor(ts, 16);
        ts += __shfl_xor(ts, 32);
        const float inv = 1.0f / ts;
        const f32x4 o0 = o0a + o0b;
        const f32x4 o1 = o1a + o1b;

        #pragma unroll
        for (int r = 0; r < 4; ++r) {
            const int row = qt * 16 + 4 * g + r;
            const float iv = __shfl(inv, 4 * g + r);
            if (row < NT) {
                op[(size_t)row * DKK + c]      = o0[r] * iv;
                op[(size_t)row * DKK + c + 16] = o1[r] * iv;
            }
        }
        qa = na; qb = nb;
    }
}

extern "C" void kernel_launch(void* const* d_in, const int* in_sizes, int n_in,
                              void* d_out, int out_size, void* d_ws, size_t ws_size,
                              hipStream_t stream) {
    const float* Qf  = (const float*)d_in[0];
    const float* Kf  = (const float*)d_in[1];
    const float* Vf  = (const float*)d_in[2];
    const float* Qs  = (const float*)d_in[3];
    const float* Ks  = (const float*)d_in[4];
    const float* Vs  = (const float*)d_in[5];
    const float* Kj  = (const float*)d_in[6];
    const float* Vfp = (const float*)d_in[7];
    float* out = (float*)d_out;

    attn_slim<<<dim3(NSL * 3), dim3(512), 0, stream>>>(Qf, Kf, Vf, Qs, Ks, Vs, out);
    attn_fat <<<dim3(NSL),     dim3(512), 0, stream>>>(Kf, Vf, Qs, Kj, Vfp, out);
}

// Round 18
// 164.537 us; speedup vs baseline: 1.6308x; 1.6308x over previous
//
#include <hip/hip_runtime.h>
#include <hip/hip_bf16.h>

typedef float f32x4  __attribute__((ext_vector_type(4)));
typedef float f32x16 __attribute__((ext_vector_type(16)));
typedef short short8 __attribute__((ext_vector_type(8)));

#define NT    325
#define DKK   32
#define NSL   384                 // B*H*T
#define SLICE (NT*DKK)            // 10400
#define TOTE  (NSL*SLICE)         // per-output-tensor elements
#define NKT   21                  // ceil(325/16) (fat kernel)
#define NQT32 11                  // ceil(325/32) (slim kernel)
#define PADV  352                 // 11*32, padded m for PV
#define VGRAN (32 * (PADV/8))     // 1408 16B-granules in Vt
// 1/sqrt(32) * log2(e)
#define SCALE2 0.25506372f

// XOR swizzle on short-index (byte bits 4..6).
__device__ __forceinline__ int swz(int sidx, int row) { return sidx ^ ((row & 7) << 3); }

__device__ __forceinline__ unsigned cvtpk(float lo, float hi) {
    unsigned r;
    asm("v_cvt_pk_bf16_f32 %0, %1, %2" : "=v"(r) : "v"(lo), "v"(hi));
    return r;
}
__device__ __forceinline__ unsigned pk2_split(float x, float y, unsigned& lopk) {
    const unsigned hi = cvtpk(x, y);
    const float hx = __builtin_bit_cast(float, hi << 16);
    const float hy = __builtin_bit_cast(float, hi & 0xffff0000u);
    lopk = cvtpk(x - hx, y - hy);
    return hi;
}
__device__ __forceinline__ void swap32(unsigned& a, unsigned& b) {
    asm("v_permlane32_swap_b32 %0, %1" : "+v"(a), "+v"(b));
}
__device__ __forceinline__ void swap16(unsigned& a, unsigned& b) {
    asm("v_permlane16_swap_b32 %0, %1" : "+v"(a), "+v"(b));
}
// 16x16 P repack (fat kernel; verified r9/r12).
__device__ __forceinline__ short8 repack(const f32x4& a0, const f32x4& a1, bool hasB) {
    unsigned u = cvtpk(a0[0], a0[1]);
    unsigned v = cvtpk(a0[2], a0[3]);
    unsigned s = hasB ? cvtpk(a1[0], a1[1]) : 0u;
    unsigned t = hasB ? cvtpk(a1[2], a1[3]) : 0u;
    swap32(u, s); swap16(u, s);
    swap32(v, t); swap16(v, t);
    uint4 w; w.x = u; w.y = v; w.z = s; w.w = t;
    return __builtin_bit_cast(short8, w);
}

// ============================ SLIM kernel (32x32 MFMA) ======================
// vars {0,2,3}. Layouts VERIFIED r17 (absmax passed); r17's failure was a spill:
// (512,3) capped VGPR at 84 < live state of the fully-unrolled loop.
// r18: launch_bounds(512,2) (cap 128, no spill) + #pragma unroll 2 (curb
// cross-iteration pressure). If regs land <=85 HW still gives 3 blocks/CU.
__global__ __launch_bounds__(512, 2)
void attn_slim(const float* __restrict__ Qf, const float* __restrict__ Kf,
               const float* __restrict__ Vf, const float* __restrict__ Qs,
               const float* __restrict__ Ks, const float* __restrict__ Vs,
               float* __restrict__ out)
{
    __shared__ __align__(16) unsigned short Kb[PADV * DKK];  // [m][d] bf16 (swizzled)
    __shared__ __align__(16) unsigned short Vt[DKK * PADV];  // [d][m] bf16 (swizzled)

    const int tid = threadIdx.x;
    const int bid = blockIdx.x;
    const int bt  = bid / 3;
    const int vr  = bid - 3 * bt;
    const int vi  = (vr + bt) % 3;
    const int var = (vi == 0) ? 0 : (vi == 1) ? 2 : 3;
    const size_t base = (size_t)bt * SLICE;

    const float *qp, *kp, *vp;
    if      (var == 0) { qp = Qf; kp = Kf; vp = Vf; }
    else if (var == 2) { qp = Ks; kp = Qf; vp = Vs; }
    else               { qp = Qs; kp = Ks; vp = Vs; }
    float* op = out + (size_t)var * TOTE + base;

    // ---- stage K -> Kb (bf16, swizzled); zero rows 325..351 ----
    for (int i8 = tid; i8 < (PADV * DKK) / 8; i8 += 512) {
        const int idx = i8 * 8;
        const int m   = idx >> 5;
        uint4 pkv;
        if (m < NT) {
            const float* s = kp + base + idx;
            const float4 a = *(const float4*)s;
            const float4 b = *(const float4*)(s + 4);
            pkv.x = cvtpk(a.x, a.y); pkv.y = cvtpk(a.z, a.w);
            pkv.z = cvtpk(b.x, b.y); pkv.w = cvtpk(b.z, b.w);
        } else {
            pkv.x = pkv.y = pkv.z = pkv.w = 0u;
        }
        *(uint4*)&Kb[swz(idx, m)] = pkv;
    }

    // ---- stage V -> Vt (bf16, transposed, zero-padded, swizzled, coalesced) ----
    for (int gi = tid; gi < VGRAN; gi += 512) {
        const int dd = gi & 31;
        const int m8 = gi >> 5;           // 0..43
        const int mb = m8 * 8;
        float v[8];
        #pragma unroll
        for (int i = 0; i < 8; ++i) {
            const int m = mb + i;
            v[i] = (m < NT) ? vp[base + (size_t)m * DKK + dd] : 0.0f;
        }
        uint4 pkv;
        pkv.x = cvtpk(v[0], v[1]); pkv.y = cvtpk(v[2], v[3]);
        pkv.z = cvtpk(v[4], v[5]); pkv.w = cvtpk(v[6], v[7]);
        *(uint4*)&Vt[swz(dd * PADV + mb, dd)] = pkv;
    }
    __syncthreads();

    const int lane = tid & 63;
    const int wv   = tid >> 6;                // 0..7
    const int l31  = lane & 31;
    const int h    = lane >> 5;               // 0,1
    const int d0   = h * 8;
    const int swz8 = (lane & 7) << 3;         // row&7 == lane&7 for all frag reads
    const f32x16 zero16 = {0,0,0,0,0,0,0,0,0,0,0,0,0,0,0,0};

    for (int qt = wv; qt < NQT32; qt += 8) {
        // Q B-frags: lane covers q = qt*32+l31, d = d0..d0+7 and 16+d0..16+d0+7
        int qr = qt * 32 + l31; if (qr > NT - 1) qr = NT - 1;
        const float* qsrc = qp + base + (size_t)qr * DKK;
        const float4 qA = *(const float4*)(qsrc + d0);
        const float4 qB = *(const float4*)(qsrc + d0 + 4);
        const float4 qC = *(const float4*)(qsrc + 16 + d0);
        const float4 qD = *(const float4*)(qsrc + 16 + d0 + 4);
        uint4 w1, w2;
        w1.x = cvtpk(qA.x * SCALE2, qA.y * SCALE2);
        w1.y = cvtpk(qA.z * SCALE2, qA.w * SCALE2);
        w1.z = cvtpk(qB.x * SCALE2, qB.y * SCALE2);
        w1.w = cvtpk(qB.z * SCALE2, qB.w * SCALE2);
        w2.x = cvtpk(qC.x * SCALE2, qC.y * SCALE2);
        w2.y = cvtpk(qC.z * SCALE2, qC.w * SCALE2);
        w2.z = cvtpk(qD.x * SCALE2, qD.y * SCALE2);
        w2.w = cvtpk(qD.z * SCALE2, qD.w * SCALE2);
        const short8 q1 = __builtin_bit_cast(short8, w1);
        const short8 q2 = __builtin_bit_cast(short8, w2);

        f32x16 o = zero16;
        float ts0 = 0.f, ts1 = 0.f, ts2 = 0.f, ts3 = 0.f;

        #pragma unroll 2
        for (int ks = 0; ks < NQT32; ++ks) {
            const int mrow = ks * 32 + l31;
            const int ki1 = (mrow * DKK + d0) ^ swz8;
            const int ki2 = (mrow * DKK + 16 + d0) ^ swz8;
            const short8 k1 = *(const short8*)&Kb[ki1];
            const short8 k2 = *(const short8*)&Kb[ki2];

            __builtin_amdgcn_s_setprio(1);
            f32x16 a = __builtin_amdgcn_mfma_f32_32x32x16_bf16(k1, q1, zero16, 0, 0, 0);
            a = __builtin_amdgcn_mfma_f32_32x32x16_bf16(k2, q2, a, 0, 0, 0);
            __builtin_amdgcn_s_setprio(0);

            if (ks == 10) {   // mask m >= 325: m_local = (r&3)+8*(r>>2)+4h > 4
                #pragma unroll
                for (int r = 0; r < 16; ++r) {
                    const int ml = (r & 3) + 8 * (r >> 2) + 4 * h;
                    a[r] = (ml > 4) ? -1e30f : a[r];
                }
            }

            // |s| small in log2 domain: no max subtraction. All 16 regs same q.
            #pragma unroll
            for (int r = 0; r < 16; ++r) a[r] = exp2f(a[r]);
            ts0 += (a[0] + a[1]) + (a[2] + a[3]);
            ts1 += (a[4] + a[5]) + (a[6] + a[7]);
            ts2 += (a[8] + a[9]) + (a[10] + a[11]);
            ts3 += (a[12] + a[13]) + (a[14] + a[15]);

            // PV A-frags: regs 0..7 -> k=m_local 0..15; regs 8..15 -> 16..31.
            unsigned u1 = cvtpk(a[0],  a[1]),  v1w = cvtpk(a[2],  a[3]);
            unsigned s1 = cvtpk(a[4],  a[5]),  t1  = cvtpk(a[6],  a[7]);
            swap32(u1, s1); swap32(v1w, t1);
            uint4 wa; wa.x = u1; wa.y = v1w; wa.z = s1; wa.w = t1;
            const short8 af1 = __builtin_bit_cast(short8, wa);
            unsigned u2 = cvtpk(a[8],  a[9]),  v2w = cvtpk(a[10], a[11]);
            unsigned s2 = cvtpk(a[12], a[13]), t2  = cvtpk(a[14], a[15]);
            swap32(u2, s2); swap32(v2w, t2);
            uint4 wb; wb.x = u2; wb.y = v2w; wb.z = s2; wb.w = t2;
            const short8 af2 = __builtin_bit_cast(short8, wb);

            // V B-frags: lane needs V[m = ks*32 + half*16 + h*8 + j][d=l31]
            const int vi1 = (l31 * PADV + ks * 32 + d0) ^ swz8;
            const int vi2 = (l31 * PADV + ks * 32 + 16 + d0) ^ swz8;
            const short8 vf1 = *(const short8*)&Vt[vi1];
            const short8 vf2 = *(const short8*)&Vt[vi2];

            __builtin_amdgcn_s_setprio(1);
            o = __builtin_amdgcn_mfma_f32_32x32x16_bf16(af1, vf1, o, 0, 0, 0);
            o = __builtin_amdgcn_mfma_f32_32x32x16_bf16(af2, vf2, o, 0, 0, 0);
            __builtin_amdgcn_s_setprio(0);
        }

        float ts = (ts0 + ts1) + (ts2 + ts3);
        ts += __shfl_xor(ts, 32);             // lane pair (l, l+32) share q = l31
        const float inv = 1.0f / ts;

        #pragma unroll
        for (int r = 0; r < 16; ++r) {
            const int ql  = (r & 3) + 8 * (r >> 2) + 4 * h;   // q within tile
            const int row = qt * 32 + ql;
            const float iv = __shfl(inv, ql);                  // lane ql holds full sum
            if (row < NT) op[(size_t)row * DKK + l31] = o[r] * iv;
        }
    }
}

// ============================= FAT kernel (r16, unchanged) ==================
__global__ __launch_bounds__(512, 2)
void attn_fat(const float* __restrict__ Kf, const float* __restrict__ Vf,
              const float* __restrict__ Qs,
              const float* __restrict__ Kj, const float* __restrict__ Vfp,
              float* __restrict__ out)
{
    __shared__ __align__(16) unsigned short Kb[336 * DKK];   // bf16 hi (swizzled)
    __shared__ __align__(16) unsigned short Kl[336 * DKK];   // bf16 lo (swizzled)
    __shared__ __align__(16) unsigned short Vt[DKK * PADV];  // [d][m] bf16 (swizzled)

    const int tid = threadIdx.x;
    const int bt  = blockIdx.x;
    const size_t base = (size_t)bt * SLICE;

    const float* qp = Kf;
    const float* kp = Qs;
    const float* vp = Vf;
    float* op = out + (size_t)1 * TOTE + base;

    for (int i8 = tid; i8 < SLICE / 8; i8 += 512) {
        const int idx = i8 * 8;
        const int m   = idx >> 5;
        const int sidx = swz(idx, m);
        const float* s = kp + base + idx;
        float4 a = *(const float4*)s;
        float4 b = *(const float4*)(s + 4);
        const float kj = Kj[m];
        const float rv = 1.0f / (Vfp[m] + 1e-5f);
        a.x = kj * (a.x - a.x * a.x * rv);
        a.y = kj * (a.y - a.y * a.y * rv);
        a.z = kj * (a.z - a.z * a.z * rv);
        a.w = kj * (a.w - a.w * a.w * rv);
        b.x = kj * (b.x - b.x * b.x * rv);
        b.y = kj * (b.y - b.y * b.y * rv);
        b.z = kj * (b.z - b.z * b.z * rv);
        b.w = kj * (b.w - b.w * b.w * rv);
        uint4 hw, lw;
        hw.x = pk2_split(a.x, a.y, lw.x);
        hw.y = pk2_split(a.z, a.w, lw.y);
        hw.z = pk2_split(b.x, b.y, lw.z);
        hw.w = pk2_split(b.z, b.w, lw.w);
        *(uint4*)&Kb[sidx] = hw;
        *(uint4*)&Kl[sidx] = lw;
    }

    for (int gi = tid; gi < VGRAN; gi += 512) {
        const int dd = gi & 31;
        const int m8 = gi >> 5;
        const int mb = m8 * 8;
        float v[8];
        #pragma unroll
        for (int i = 0; i < 8; ++i) {
            const int m = mb + i;
            v[i] = (m < NT) ? vp[base + (size_t)m * DKK + dd] : 0.0f;
        }
        uint4 pkv;
        pkv.x = cvtpk(v[0], v[1]); pkv.y = cvtpk(v[2], v[3]);
        pkv.z = cvtpk(v[4], v[5]); pkv.w = cvtpk(v[6], v[7]);
        *(uint4*)&Vt[swz(dd * PADV + mb, dd)] = pkv;
    }
    __syncthreads();

    const int lane = tid & 63;
    const int wv   = tid >> 6;
    const int c    = lane & 15;
    const int g    = lane >> 4;
    const int kswz = (c & 7) << 3;
    const f32x4 zero = {0.f, 0.f, 0.f, 0.f};

    int qt = wv;
    float4 qa, qb;
    {
        int qr = qt * 16 + c; if (qr > NT - 1) qr = NT - 1;
        const float* s = qp + base + (size_t)qr * DKK + g * 8;
        qa = *(const float4*)s; qb = *(const float4*)(s + 4);
    }

    for (; qt < NKT; qt += 8) {
        float4 na, nb;
        const bool more = (qt + 8) < NKT;
        if (more) {
            int qr = (qt + 8) * 16 + c; if (qr > NT - 1) qr = NT - 1;
            const float* s = qp + base + (size_t)qr * DKK + g * 8;
            na = *(const float4*)s; nb = *(const float4*)(s + 4);
        }

        uint4 qwh, qwl;
        qwh.x = pk2_split(qa.x * SCALE2, qa.y * SCALE2, qwl.x);
        qwh.y = pk2_split(qa.z * SCALE2, qa.w * SCALE2, qwl.y);
        qwh.z = pk2_split(qb.x * SCALE2, qb.y * SCALE2, qwl.z);
        qwh.w = pk2_split(qb.z * SCALE2, qb.w * SCALE2, qwl.w);
        const short8 qh = __builtin_bit_cast(short8, qwh);
        const short8 ql = __builtin_bit_cast(short8, qwl);

        f32x4 o0a = zero, o1a = zero, o0b = zero, o1b = zero;
        float ts0 = 0.f, ts1 = 0.f, ts2 = 0.f, ts3 = 0.f;
        float mrow = -1e30f;

        #pragma unroll
        for (int ks = 0; ks < 11; ++ks) {
            const int fi0 = (((2 * ks) * 16 + c) * DKK + g * 8) ^ kswz;
            const int fi1 = fi0 + 16 * DKK;
            const bool hasB1 = (ks < 10);
            f32x4 a0, a1;

            __builtin_amdgcn_s_setprio(1);
            {
                const short8 kh = *(const short8*)&Kb[fi0];
                const short8 kl = *(const short8*)&Kl[fi0];
                f32x4 t = __builtin_amdgcn_mfma_f32_16x16x32_bf16(kh, ql, zero, 0, 0, 0);
                t = __builtin_amdgcn_mfma_f32_16x16x32_bf16(kl, qh, t, 0, 0, 0);
                a0 = __builtin_amdgcn_mfma_f32_16x16x32_bf16(kh, qh, t, 0, 0, 0);
            }
            if (hasB1) {
                const short8 kh = *(const short8*)&Kb[fi1];
                const short8 kl = *(const short8*)&Kl[fi1];
                f32x4 t = __builtin_amdgcn_mfma_f32_16x16x32_bf16(kh, ql, zero, 0, 0, 0);
                t = __builtin_amdgcn_mfma_f32_16x16x32_bf16(kl, qh, t, 0, 0, 0);
                a1 = __builtin_amdgcn_mfma_f32_16x16x32_bf16(kh, qh, t, 0, 0, 0);
            }
            __builtin_amdgcn_s_setprio(0);

            if (ks == 10) {
                #pragma unroll
                for (int r = 0; r < 4; ++r)
                    a0[r] = (4 * g + r > 4) ? -1e30f : a0[r];
            }

            float pm = fmaxf(fmaxf(a0[0], a0[1]), fmaxf(a0[2], a0[3]));
            if (hasB1)
                pm = fmaxf(pm, fmaxf(fmaxf(a1[0], a1[1]), fmaxf(a1[2], a1[3])));
            pm = fmaxf(pm, __shfl_xor(pm, 16));
            pm = fmaxf(pm, __shfl_xor(pm, 32));
            if (__any(pm > mrow)) {
                const float mn = fmaxf(mrow, pm);
                const float f = exp2f(mrow - mn);
                mrow = mn;
                ts0 *= f; ts1 *= f; ts2 *= f; ts3 *= f;
                #pragma unroll
                for (int r = 0; r < 4; ++r) {
                    const float fr = __shfl(f, 4 * g + r);
                    o0a[r] *= fr; o1a[r] *= fr;
                    o0b[r] *= fr; o1b[r] *= fr;
                }
            }
            a0[0] = exp2f(a0[0] - mrow); a0[1] = exp2f(a0[1] - mrow);
            a0[2] = exp2f(a0[2] - mrow); a0[3] = exp2f(a0[3] - mrow);
            ts0 += a0[0]; ts1 += a0[1]; ts2 += a0[2]; ts3 += a0[3];
            if (hasB1) {
                a1[0] = exp2f(a1[0] - mrow); a1[1] = exp2f(a1[1] - mrow);
                a1[2] = exp2f(a1[2] - mrow); a1[3] = exp2f(a1[3] - mrow);
                ts0 += a1[0]; ts1 += a1[1]; ts2 += a1[2]; ts3 += a1[3];
            }

            const short8 af = repack(a0, hasB1 ? a1 : a0, hasB1);
            const short8 v0 = *(const short8*)&Vt[( c        * PADV + ks * 32 + g * 8) ^ kswz];
            const short8 v1 = *(const short8*)&Vt[((c + 16)  * PADV + ks * 32 + g * 8) ^ kswz];
            __builtin_amdgcn_s_setprio(1);
            if (ks & 1) {
                o0b = __builtin_amdgcn_mfma_f32_16x16x32_bf16(af, v0, o0b, 0, 0, 0);
                o1b = __builtin_amdgcn_mfma_f32_16x16x32_bf16(af, v1, o1b, 0, 0, 0);
            } else {
                o0a = __builtin_amdgcn_mfma_f32_16x16x32_bf16(af, v0, o0a, 0, 0, 0);
                o1a = __builtin_amdgcn_mfma_f32_16x16x32_bf16(af, v1, o1a, 0, 0, 0);
            }
            __builtin_amdgcn_s_setprio(0);
        }

        float ts = (ts0 + ts1) + (ts2 + ts3);
        ts += __shfl_xor(ts, 16);
        ts += __shfl_xor(ts, 32);
        const float inv = 1.0f / ts;
        const f32x4 o0 = o0a + o0b;
        const f32x4 o1 = o1a + o1b;

        #pragma unroll
        for (int r = 0; r < 4; ++r) {
            const int row = qt * 16 + 4 * g + r;
            const float iv = __shfl(inv, 4 * g + r);
            if (row < NT) {
                op[(size_t)row * DKK + c]      = o0[r] * iv;
                op[(size_t)row * DKK + c + 16] = o1[r] * iv;
            }
        }
        qa = na; qb = nb;
    }
}

extern "C" void kernel_launch(void* const* d_in, const int* in_sizes, int n_in,
                              void* d_out, int out_size, void* d_ws, size_t ws_size,
                              hipStream_t stream) {
    const float* Qf  = (const float*)d_in[0];
    const float* Kf  = (const float*)d_in[1];
    const float* Vf  = (const float*)d_in[2];
    const float* Qs  = (const float*)d_in[3];
    const float* Ks  = (const float*)d_in[4];
    const float* Vs  = (const float*)d_in[5];
    const float* Kj  = (const float*)d_in[6];
    const float* Vfp = (const float*)d_in[7];
    float* out = (float*)d_out;

    attn_slim<<<dim3(NSL * 3), dim3(512), 0, stream>>>(Qf, Kf, Vf, Qs, Ks, Vs, out);
    attn_fat <<<dim3(NSL),     dim3(512), 0, stream>>>(Kf, Vf, Qs, Kj, Vfp, out);
}

// Round 20
// 102.525 us; speedup vs baseline: 2.6171x; 1.6048x over previous
//
#include <hip/hip_runtime.h>
#include <hip/hip_bf16.h>

typedef float f32x4 __attribute__((ext_vector_type(4)));
typedef short short8 __attribute__((ext_vector_type(8)));

#define NT    325
#define DKK   32
#define NSL   384                 // B*H*T
#define SLICE (NT*DKK)            // 10400
#define TOTE  (NSL*SLICE)         // per-output-tensor elements
#define NKT   21                  // ceil(325/16)
#define PADV  352                 // 11*32, padded m for PV
#define VGRAN (32 * (PADV/8))     // 1408 16B-granules in Vt
// 1/sqrt(32) * log2(e): scores in log2 domain, exp -> exp2f
#define SCALE2 0.25506372f

// XOR swizzle on short-index (byte bits 4..6).
__device__ __forceinline__ int swz(int sidx, int row) { return sidx ^ ((row & 7) << 3); }

// HW packed f32->bf16 pair convert.
__device__ __forceinline__ unsigned cvtpk(float lo, float hi) {
    unsigned r;
    asm("v_cvt_pk_bf16_f32 %0, %1, %2" : "=v"(r) : "v"(lo), "v"(hi));
    return r;
}
// split (x,y) -> bf16-hi packed word (returned) + bf16-lo packed word (Markidis)
__device__ __forceinline__ unsigned pk2_split(float x, float y, unsigned& lopk) {
    const unsigned hi = cvtpk(x, y);
    const float hx = __builtin_bit_cast(float, hi << 16);
    const float hy = __builtin_bit_cast(float, hi & 0xffff0000u);
    lopk = cvtpk(x - hx, y - hy);
    return hi;
}
// gfx950 register-file lane swaps (no LDS pipe).
__device__ __forceinline__ void swap32(unsigned& a, unsigned& b) {
    asm("v_permlane32_swap_b32 %0, %1" : "+v"(a), "+v"(b));
}
__device__ __forceinline__ void swap16(unsigned& a, unsigned& b) {
    asm("v_permlane16_swap_b32 %0, %1" : "+v"(a), "+v"(b));
}
// P repack fully in registers (verified r9/r10/r12): af[j] = P[q=c][m=32ks+8g+j].
__device__ __forceinline__ short8 repack(const f32x4& a0, const f32x4& a1, bool hasB) {
    unsigned u = cvtpk(a0[0], a0[1]);
    unsigned v = cvtpk(a0[2], a0[3]);
    unsigned s = hasB ? cvtpk(a1[0], a1[1]) : 0u;
    unsigned t = hasB ? cvtpk(a1[2], a1[3]) : 0u;
    swap32(u, s); swap16(u, s);
    swap32(v, t); swap16(v, t);
    uint4 w; w.x = u; w.y = v; w.z = s; w.w = t;
    return __builtin_bit_cast(short8, w);
}

// ============================ SLIM kernel ===================================
// vars {0,2,3}: no Kl, no split MFMA, no online max. LDS 44032 -> 3 blocks/CU.
// V staging index map (dd = gi&31, m8 = gi>>5) -> global reads COALESCED.
// (r16 build, fully validated incl. post-timing; r17-r19's 32x32 variant was
// faster but non-deterministic under graph replay -> abandoned.)
__global__ __launch_bounds__(512, 3)
void attn_slim(const float* __restrict__ Qf, const float* __restrict__ Kf,
               const float* __restrict__ Vf, const float* __restrict__ Qs,
               const float* __restrict__ Ks, const float* __restrict__ Vs,
               float* __restrict__ out)
{
    __shared__ __align__(16) unsigned short Kb[336 * DKK];   // [m][d] bf16 (swizzled)
    __shared__ __align__(16) unsigned short Vt[DKK * PADV];  // [d][m] bf16 (swizzled)

    const int tid = threadIdx.x;
    const int bid = blockIdx.x;
    const int bt  = bid / 3;
    const int vr  = bid - 3 * bt;
    const int vi  = (vr + bt) % 3;
    const int var = (vi == 0) ? 0 : (vi == 1) ? 2 : 3;
    const size_t base = (size_t)bt * SLICE;

    const float *qp, *kp, *vp;
    if      (var == 0) { qp = Qf; kp = Kf; vp = Vf; }
    else if (var == 2) { qp = Ks; kp = Qf; vp = Vs; }
    else               { qp = Qs; kp = Ks; vp = Vs; }
    float* op = out + (size_t)var * TOTE + base;

    // ---- stage K -> Kb (bf16) ----
    for (int i8 = tid; i8 < SLICE / 8; i8 += 512) {
        const int idx = i8 * 8;
        const int m   = idx >> 5;
        const float* s = kp + base + idx;
        const float4 a = *(const float4*)s;
        const float4 b = *(const float4*)(s + 4);
        uint4 pkv;
        pkv.x = cvtpk(a.x, a.y); pkv.y = cvtpk(a.z, a.w);
        pkv.z = cvtpk(b.x, b.y); pkv.w = cvtpk(b.z, b.w);
        *(uint4*)&Kb[swz(idx, m)] = pkv;
    }

    // ---- stage V -> Vt (bf16, transposed, zero-padded, swizzled) ----
    // dd = gi&31: for each i, lanes 0..31 read 128B contiguous (coalesced).
    for (int gi = tid; gi < VGRAN; gi += 512) {
        const int dd = gi & 31;
        const int m8 = gi >> 5;           // 0..43
        const int mb = m8 * 8;
        float v[8];
        #pragma unroll
        for (int i = 0; i < 8; ++i) {
            const int m = mb + i;
            v[i] = (m < NT) ? vp[base + (size_t)m * DKK + dd] : 0.0f;
        }
        uint4 pkv;
        pkv.x = cvtpk(v[0], v[1]); pkv.y = cvtpk(v[2], v[3]);
        pkv.z = cvtpk(v[4], v[5]); pkv.w = cvtpk(v[6], v[7]);
        *(uint4*)&Vt[swz(dd * PADV + mb, dd)] = pkv;
    }
    __syncthreads();

    const int lane = tid & 63;
    const int wv   = tid >> 6;                // 0..7
    const int c    = lane & 15;
    const int g    = lane >> 4;
    const int kswz = (c & 7) << 3;
    const f32x4 zero = {0.f, 0.f, 0.f, 0.f};

    int qt = wv;
    float4 qa, qb;
    {   // preload first Q frag
        int qr = qt * 16 + c; if (qr > NT - 1) qr = NT - 1;
        const float* s = qp + base + (size_t)qr * DKK + g * 8;
        qa = *(const float4*)s; qb = *(const float4*)(s + 4);
    }

    for (; qt < NKT; qt += 8) {
        float4 na, nb;
        const bool more = (qt + 8) < NKT;
        if (more) {
            int qr = (qt + 8) * 16 + c; if (qr > NT - 1) qr = NT - 1;
            const float* s = qp + base + (size_t)qr * DKK + g * 8;
            na = *(const float4*)s; nb = *(const float4*)(s + 4);
        }

        uint4 qwh;
        qwh.x = cvtpk(qa.x * SCALE2, qa.y * SCALE2);
        qwh.y = cvtpk(qa.z * SCALE2, qa.w * SCALE2);
        qwh.z = cvtpk(qb.x * SCALE2, qb.y * SCALE2);
        qwh.w = cvtpk(qb.z * SCALE2, qb.w * SCALE2);
        const short8 qh = __builtin_bit_cast(short8, qwh);

        f32x4 o0a = zero, o1a = zero, o0b = zero, o1b = zero;   // even/odd chunk accums
        float ts0 = 0.f, ts1 = 0.f, ts2 = 0.f, ts3 = 0.f;       // per-r partial sums

        #pragma unroll
        for (int ks = 0; ks < 11; ++ks) {
            const int fi0 = (((2 * ks) * 16 + c) * DKK + g * 8) ^ kswz;
            const int fi1 = fi0 + 16 * DKK;     // +512: swizzle bits untouched
            const bool hasB1 = (ks < 10);
            f32x4 a0, a1;

            __builtin_amdgcn_s_setprio(1);
            {
                const short8 k0 = *(const short8*)&Kb[fi0];
                a0 = __builtin_amdgcn_mfma_f32_16x16x32_bf16(k0, qh, zero, 0, 0, 0);
                if (hasB1) {
                    const short8 k1 = *(const short8*)&Kb[fi1];
                    a1 = __builtin_amdgcn_mfma_f32_16x16x32_bf16(k1, qh, zero, 0, 0, 0);
                }
            }
            __builtin_amdgcn_s_setprio(0);

            if (ks == 10) {   // mask m >= 325 (tile 20: m = 320 + 4g + r)
                #pragma unroll
                for (int r = 0; r < 4; ++r)
                    a0[r] = (4 * g + r > 4) ? -1e30f : a0[r];
            }

            // |s| <= ~9 in log2 domain: no max subtraction needed
            a0[0] = exp2f(a0[0]); a0[1] = exp2f(a0[1]);
            a0[2] = exp2f(a0[2]); a0[3] = exp2f(a0[3]);
            ts0 += a0[0]; ts1 += a0[1]; ts2 += a0[2]; ts3 += a0[3];
            if (hasB1) {
                a1[0] = exp2f(a1[0]); a1[1] = exp2f(a1[1]);
                a1[2] = exp2f(a1[2]); a1[3] = exp2f(a1[3]);
                ts0 += a1[0]; ts1 += a1[1]; ts2 += a1[2]; ts3 += a1[3];
            }

            const short8 af = repack(a0, hasB1 ? a1 : a0, hasB1);
            const short8 v0 = *(const short8*)&Vt[( c        * PADV + ks * 32 + g * 8) ^ kswz];
            const short8 v1 = *(const short8*)&Vt[((c + 16)  * PADV + ks * 32 + g * 8) ^ kswz];
            __builtin_amdgcn_s_setprio(1);
            if (ks & 1) {
                o0b = __builtin_amdgcn_mfma_f32_16x16x32_bf16(af, v0, o0b, 0, 0, 0);
                o1b = __builtin_amdgcn_mfma_f32_16x16x32_bf16(af, v1, o1b, 0, 0, 0);
            } else {
                o0a = __builtin_amdgcn_mfma_f32_16x16x32_bf16(af, v0, o0a, 0, 0, 0);
                o1a = __builtin_amdgcn_mfma_f32_16x16x32_bf16(af, v1, o1a, 0, 0, 0);
            }
            __builtin_amdgcn_s_setprio(0);
        }

        float ts = (ts0 + ts1) + (ts2 + ts3);
        ts += __shfl_xor(ts, 16);
        ts += __shfl_xor(ts, 32);
        const float inv = 1.0f / ts;
        const f32x4 o0 = o0a + o0b;
        const f32x4 o1 = o1a + o1b;

        #pragma unroll
        for (int r = 0; r < 4; ++r) {
            const int row = qt * 16 + 4 * g + r;
            const float iv = __shfl(inv, 4 * g + r);
            if (row < NT) {
                op[(size_t)row * DKK + c]      = o0[r] * iv;
                op[(size_t)row * DKK + c + 16] = o1[r] * iv;
            }
        }
        qa = na; qb = nb;
    }
}

// ============================= FAT kernel ===================================
// var 1 only (K = FlowSpeed(Qs), |K| ~1e3): 3-term bf16-split MFMA + online max
// with wave-uniform defer-skip. 384 blocks -> all resident at 2/CU.
__global__ __launch_bounds__(512, 2)
void attn_fat(const float* __restrict__ Kf, const float* __restrict__ Vf,
              const float* __restrict__ Qs,
              const float* __restrict__ Kj, const float* __restrict__ Vfp,
              float* __restrict__ out)
{
    __shared__ __align__(16) unsigned short Kb[336 * DKK];   // bf16 hi (swizzled)
    __shared__ __align__(16) unsigned short Kl[336 * DKK];   // bf16 lo (swizzled)
    __shared__ __align__(16) unsigned short Vt[DKK * PADV];  // [d][m] bf16 (swizzled)

    const int tid = threadIdx.x;
    const int bt  = blockIdx.x;
    const size_t base = (size_t)bt * SLICE;

    const float* qp = Kf;
    const float* kp = Qs;
    const float* vp = Vf;
    float* op = out + (size_t)1 * TOTE + base;

    // ---- stage K -> Kb (hi) + Kl (lo), FlowSpeed applied ----
    for (int i8 = tid; i8 < SLICE / 8; i8 += 512) {
        const int idx = i8 * 8;
        const int m   = idx >> 5;
        const int sidx = swz(idx, m);
        const float* s = kp + base + idx;
        float4 a = *(const float4*)s;
        float4 b = *(const float4*)(s + 4);
        const float kj = Kj[m];
        const float rv = 1.0f / (Vfp[m] + 1e-5f);
        a.x = kj * (a.x - a.x * a.x * rv);
        a.y = kj * (a.y - a.y * a.y * rv);
        a.z = kj * (a.z - a.z * a.z * rv);
        a.w = kj * (a.w - a.w * a.w * rv);
        b.x = kj * (b.x - b.x * b.x * rv);
        b.y = kj * (b.y - b.y * b.y * rv);
        b.z = kj * (b.z - b.z * b.z * rv);
        b.w = kj * (b.w - b.w * b.w * rv);
        uint4 hw, lw;
        hw.x = pk2_split(a.x, a.y, lw.x);
        hw.y = pk2_split(a.z, a.w, lw.y);
        hw.z = pk2_split(b.x, b.y, lw.z);
        hw.w = pk2_split(b.z, b.w, lw.w);
        *(uint4*)&Kb[sidx] = hw;
        *(uint4*)&Kl[sidx] = lw;
    }

    // ---- stage V -> Vt (coalesced map) ----
    for (int gi = tid; gi < VGRAN; gi += 512) {
        const int dd = gi & 31;
        const int m8 = gi >> 5;
        const int mb = m8 * 8;
        float v[8];
        #pragma unroll
        for (int i = 0; i < 8; ++i) {
            const int m = mb + i;
            v[i] = (m < NT) ? vp[base + (size_t)m * DKK + dd] : 0.0f;
        }
        uint4 pkv;
        pkv.x = cvtpk(v[0], v[1]); pkv.y = cvtpk(v[2], v[3]);
        pkv.z = cvtpk(v[4], v[5]); pkv.w = cvtpk(v[6], v[7]);
        *(uint4*)&Vt[swz(dd * PADV + mb, dd)] = pkv;
    }
    __syncthreads();

    const int lane = tid & 63;
    const int wv   = tid >> 6;
    const int c    = lane & 15;
    const int g    = lane >> 4;
    const int kswz = (c & 7) << 3;
    const f32x4 zero = {0.f, 0.f, 0.f, 0.f};

    int qt = wv;
    float4 qa, qb;
    {
        int qr = qt * 16 + c; if (qr > NT - 1) qr = NT - 1;
        const float* s = qp + base + (size_t)qr * DKK + g * 8;
        qa = *(const float4*)s; qb = *(const float4*)(s + 4);
    }

    for (; qt < NKT; qt += 8) {
        float4 na, nb;
        const bool more = (qt + 8) < NKT;
        if (more) {
            int qr = (qt + 8) * 16 + c; if (qr > NT - 1) qr = NT - 1;
            const float* s = qp + base + (size_t)qr * DKK + g * 8;
            na = *(const float4*)s; nb = *(const float4*)(s + 4);
        }

        uint4 qwh, qwl;
        qwh.x = pk2_split(qa.x * SCALE2, qa.y * SCALE2, qwl.x);
        qwh.y = pk2_split(qa.z * SCALE2, qa.w * SCALE2, qwl.y);
        qwh.z = pk2_split(qb.x * SCALE2, qb.y * SCALE2, qwl.z);
        qwh.w = pk2_split(qb.z * SCALE2, qb.w * SCALE2, qwl.w);
        const short8 qh = __builtin_bit_cast(short8, qwh);
        const short8 ql = __builtin_bit_cast(short8, qwl);

        f32x4 o0a = zero, o1a = zero, o0b = zero, o1b = zero;
        float ts0 = 0.f, ts1 = 0.f, ts2 = 0.f, ts3 = 0.f;
        float mrow = -1e30f;

        #pragma unroll
        for (int ks = 0; ks < 11; ++ks) {
            const int fi0 = (((2 * ks) * 16 + c) * DKK + g * 8) ^ kswz;
            const int fi1 = fi0 + 16 * DKK;
            const bool hasB1 = (ks < 10);
            f32x4 a0, a1;

            __builtin_amdgcn_s_setprio(1);
            {
                const short8 kh = *(const short8*)&Kb[fi0];
                const short8 kl = *(const short8*)&Kl[fi0];
                f32x4 t = __builtin_amdgcn_mfma_f32_16x16x32_bf16(kh, ql, zero, 0, 0, 0);
                t = __builtin_amdgcn_mfma_f32_16x16x32_bf16(kl, qh, t, 0, 0, 0);
                a0 = __builtin_amdgcn_mfma_f32_16x16x32_bf16(kh, qh, t, 0, 0, 0);
            }
            if (hasB1) {
                const short8 kh = *(const short8*)&Kb[fi1];
                const short8 kl = *(const short8*)&Kl[fi1];
                f32x4 t = __builtin_amdgcn_mfma_f32_16x16x32_bf16(kh, ql, zero, 0, 0, 0);
                t = __builtin_amdgcn_mfma_f32_16x16x32_bf16(kl, qh, t, 0, 0, 0);
                a1 = __builtin_amdgcn_mfma_f32_16x16x32_bf16(kh, qh, t, 0, 0, 0);
            }
            __builtin_amdgcn_s_setprio(0);

            if (ks == 10) {
                #pragma unroll
                for (int r = 0; r < 4; ++r)
                    a0[r] = (4 * g + r > 4) ? -1e30f : a0[r];
            }

            float pm = fmaxf(fmaxf(a0[0], a0[1]), fmaxf(a0[2], a0[3]));
            if (hasB1)
                pm = fmaxf(pm, fmaxf(fmaxf(a1[0], a1[1]), fmaxf(a1[2], a1[3])));
            pm = fmaxf(pm, __shfl_xor(pm, 16));
            pm = fmaxf(pm, __shfl_xor(pm, 32));
            if (__any(pm > mrow)) {          // wave-uniform defer-skip
                const float mn = fmaxf(mrow, pm);
                const float f = exp2f(mrow - mn);   // 0 on first chunk
                mrow = mn;
                ts0 *= f; ts1 *= f; ts2 *= f; ts3 *= f;
                #pragma unroll
                for (int r = 0; r < 4; ++r) {
                    const float fr = __shfl(f, 4 * g + r);
                    o0a[r] *= fr; o1a[r] *= fr;
                    o0b[r] *= fr; o1b[r] *= fr;
                }
            }
            a0[0] = exp2f(a0[0] - mrow); a0[1] = exp2f(a0[1] - mrow);
            a0[2] = exp2f(a0[2] - mrow); a0[3] = exp2f(a0[3] - mrow);
            ts0 += a0[0]; ts1 += a0[1]; ts2 += a0[2]; ts3 += a0[3];
            if (hasB1) {
                a1[0] = exp2f(a1[0] - mrow); a1[1] = exp2f(a1[1] - mrow);
                a1[2] = exp2f(a1[2] - mrow); a1[3] = exp2f(a1[3] - mrow);
                ts0 += a1[0]; ts1 += a1[1]; ts2 += a1[2]; ts3 += a1[3];
            }

            const short8 af = repack(a0, hasB1 ? a1 : a0, hasB1);
            const short8 v0 = *(const short8*)&Vt[( c        * PADV + ks * 32 + g * 8) ^ kswz];
            const short8 v1 = *(const short8*)&Vt[((c + 16)  * PADV + ks * 32 + g * 8) ^ kswz];
            __builtin_amdgcn_s_setprio(1);
            if (ks & 1) {
                o0b = __builtin_amdgcn_mfma_f32_16x16x32_bf16(af, v0, o0b, 0, 0, 0);
                o1b = __builtin_amdgcn_mfma_f32_16x16x32_bf16(af, v1, o1b, 0, 0, 0);
            } else {
                o0a = __builtin_amdgcn_mfma_f32_16x16x32_bf16(af, v0, o0a, 0, 0, 0);
                o1a = __builtin_amdgcn_mfma_f32_16x16x32_bf16(af, v1, o1a, 0, 0, 0);
            }
            __builtin_amdgcn_s_setprio(0);
        }

        float ts = (ts0 + ts1) + (ts2 + ts3);
        ts += __shfl_xor(ts, 16);
        ts += __shfl_xor(ts, 32);
        const float inv = 1.0f / ts;
        const f32x4 o0 = o0a + o0b;
        const f32x4 o1 = o1a + o1b;

        #pragma unroll
        for (int r = 0; r < 4; ++r) {
            const int row = qt * 16 + 4 * g + r;
            const float iv = __shfl(inv, 4 * g + r);
            if (row < NT) {
                op[(size_t)row * DKK + c]      = o0[r] * iv;
                op[(size_t)row * DKK + c + 16] = o1[r] * iv;
            }
        }
        qa = na; qb = nb;
    }
}

extern "C" void kernel_launch(void* const* d_in, const int* in_sizes, int n_in,
                              void* d_out, int out_size, void* d_ws, size_t ws_size,
                              hipStream_t stream) {
    const float* Qf  = (const float*)d_in[0];
    const float* Kf  = (const float*)d_in[1];
    const float* Vf  = (const float*)d_in[2];
    const float* Qs  = (const float*)d_in[3];
    const float* Ks  = (const float*)d_in[4];
    const float* Vs  = (const float*)d_in[5];
    const float* Kj  = (const float*)d_in[6];
    const float* Vfp = (const float*)d_in[7];
    float* out = (float*)d_out;

    attn_slim<<<dim3(NSL * 3), dim3(512), 0, stream>>>(Qf, Kf, Vf, Qs, Ks, Vs, out);
    attn_fat <<<dim3(NSL),     dim3(512), 0, stream>>>(Kf, Vf, Qs, Kj, Vfp, out);
}

// Round 21
// 97.504 us; speedup vs baseline: 2.7519x; 1.0515x over previous
//
#include <hip/hip_runtime.h>
#include <hip/hip_bf16.h>

typedef float f32x4 __attribute__((ext_vector_type(4)));
typedef short short8 __attribute__((ext_vector_type(8)));

#define NT    325
#define DKK   32
#define NSL   384                 // B*H*T
#define SLICE (NT*DKK)            // 10400
#define TOTE  (NSL*SLICE)         // per-output-tensor elements
#define NKT   21                  // ceil(325/16)
#define PADV  352                 // 11*32, padded m for PV
#define VGRAN (32 * (PADV/8))     // 1408 16B-granules in Vt
// 1/sqrt(32) * log2(e): scores in log2 domain, exp -> exp2f
#define SCALE2 0.25506372f

// XOR swizzle on short-index (byte bits 4..6).
__device__ __forceinline__ int swz(int sidx, int row) { return sidx ^ ((row & 7) << 3); }

// HW packed f32->bf16 pair convert.
__device__ __forceinline__ unsigned cvtpk(float lo, float hi) {
    unsigned r;
    asm("v_cvt_pk_bf16_f32 %0, %1, %2" : "=v"(r) : "v"(lo), "v"(hi));
    return r;
}
// split (x,y) -> bf16-hi packed word (returned) + bf16-lo packed word (Markidis)
__device__ __forceinline__ unsigned pk2_split(float x, float y, unsigned& lopk) {
    const unsigned hi = cvtpk(x, y);
    const float hx = __builtin_bit_cast(float, hi << 16);
    const float hy = __builtin_bit_cast(float, hi & 0xffff0000u);
    lopk = cvtpk(x - hx, y - hy);
    return hi;
}
// gfx950 register-file lane swaps (no LDS pipe).
__device__ __forceinline__ void swap32(unsigned& a, unsigned& b) {
    asm("v_permlane32_swap_b32 %0, %1" : "+v"(a), "+v"(b));
}
__device__ __forceinline__ void swap16(unsigned& a, unsigned& b) {
    asm("v_permlane16_swap_b32 %0, %1" : "+v"(a), "+v"(b));
}
// P repack fully in registers (verified r9/r10/r12): af[j] = P[q=c][m=32ks+8g+j].
__device__ __forceinline__ short8 repack(const f32x4& a0, const f32x4& a1, bool hasB) {
    unsigned u = cvtpk(a0[0], a0[1]);
    unsigned v = cvtpk(a0[2], a0[3]);
    unsigned s = hasB ? cvtpk(a1[0], a1[1]) : 0u;
    unsigned t = hasB ? cvtpk(a1[2], a1[3]) : 0u;
    swap32(u, s); swap16(u, s);
    swap32(v, t); swap16(v, t);
    uint4 w; w.x = u; w.y = v; w.z = s; w.w = t;
    return __builtin_bit_cast(short8, w);
}

// ============================ SLIM kernel ===================================
// vars {0,2,3}: no Kl, no split MFMA, no online max. LDS 44032 -> 3 blocks/CU.
// V staging index map (dd = gi&31, m8 = gi>>5) -> global reads COALESCED.
// (r16/r20 build, fully validated incl. post-timing; UNCHANGED this round.)
__global__ __launch_bounds__(512, 3)
void attn_slim(const float* __restrict__ Qf, const float* __restrict__ Kf,
               const float* __restrict__ Vf, const float* __restrict__ Qs,
               const float* __restrict__ Ks, const float* __restrict__ Vs,
               float* __restrict__ out)
{
    __shared__ __align__(16) unsigned short Kb[336 * DKK];   // [m][d] bf16 (swizzled)
    __shared__ __align__(16) unsigned short Vt[DKK * PADV];  // [d][m] bf16 (swizzled)

    const int tid = threadIdx.x;
    const int bid = blockIdx.x;
    const int bt  = bid / 3;
    const int vr  = bid - 3 * bt;
    const int vi  = (vr + bt) % 3;
    const int var = (vi == 0) ? 0 : (vi == 1) ? 2 : 3;
    const size_t base = (size_t)bt * SLICE;

    const float *qp, *kp, *vp;
    if      (var == 0) { qp = Qf; kp = Kf; vp = Vf; }
    else if (var == 2) { qp = Ks; kp = Qf; vp = Vs; }
    else               { qp = Qs; kp = Ks; vp = Vs; }
    float* op = out + (size_t)var * TOTE + base;

    // ---- stage K -> Kb (bf16) ----
    for (int i8 = tid; i8 < SLICE / 8; i8 += 512) {
        const int idx = i8 * 8;
        const int m   = idx >> 5;
        const float* s = kp + base + idx;
        const float4 a = *(const float4*)s;
        const float4 b = *(const float4*)(s + 4);
        uint4 pkv;
        pkv.x = cvtpk(a.x, a.y); pkv.y = cvtpk(a.z, a.w);
        pkv.z = cvtpk(b.x, b.y); pkv.w = cvtpk(b.z, b.w);
        *(uint4*)&Kb[swz(idx, m)] = pkv;
    }

    // ---- stage V -> Vt (bf16, transposed, zero-padded, swizzled) ----
    for (int gi = tid; gi < VGRAN; gi += 512) {
        const int dd = gi & 31;
        const int m8 = gi >> 5;           // 0..43
        const int mb = m8 * 8;
        float v[8];
        #pragma unroll
        for (int i = 0; i < 8; ++i) {
            const int m = mb + i;
            v[i] = (m < NT) ? vp[base + (size_t)m * DKK + dd] : 0.0f;
        }
        uint4 pkv;
        pkv.x = cvtpk(v[0], v[1]); pkv.y = cvtpk(v[2], v[3]);
        pkv.z = cvtpk(v[4], v[5]); pkv.w = cvtpk(v[6], v[7]);
        *(uint4*)&Vt[swz(dd * PADV + mb, dd)] = pkv;
    }
    __syncthreads();

    const int lane = tid & 63;
    const int wv   = tid >> 6;                // 0..7
    const int c    = lane & 15;
    const int g    = lane >> 4;
    const int kswz = (c & 7) << 3;
    const f32x4 zero = {0.f, 0.f, 0.f, 0.f};

    int qt = wv;
    float4 qa, qb;
    {   // preload first Q frag
        int qr = qt * 16 + c; if (qr > NT - 1) qr = NT - 1;
        const float* s = qp + base + (size_t)qr * DKK + g * 8;
        qa = *(const float4*)s; qb = *(const float4*)(s + 4);
    }

    for (; qt < NKT; qt += 8) {
        float4 na, nb;
        const bool more = (qt + 8) < NKT;
        if (more) {
            int qr = (qt + 8) * 16 + c; if (qr > NT - 1) qr = NT - 1;
            const float* s = qp + base + (size_t)qr * DKK + g * 8;
            na = *(const float4*)s; nb = *(const float4*)(s + 4);
        }

        uint4 qwh;
        qwh.x = cvtpk(qa.x * SCALE2, qa.y * SCALE2);
        qwh.y = cvtpk(qa.z * SCALE2, qa.w * SCALE2);
        qwh.z = cvtpk(qb.x * SCALE2, qb.y * SCALE2);
        qwh.w = cvtpk(qb.z * SCALE2, qb.w * SCALE2);
        const short8 qh = __builtin_bit_cast(short8, qwh);

        f32x4 o0a = zero, o1a = zero, o0b = zero, o1b = zero;   // even/odd chunk accums
        float ts0 = 0.f, ts1 = 0.f, ts2 = 0.f, ts3 = 0.f;       // per-r partial sums

        #pragma unroll
        for (int ks = 0; ks < 11; ++ks) {
            const int fi0 = (((2 * ks) * 16 + c) * DKK + g * 8) ^ kswz;
            const int fi1 = fi0 + 16 * DKK;     // +512: swizzle bits untouched
            const bool hasB1 = (ks < 10);
            f32x4 a0, a1;

            __builtin_amdgcn_s_setprio(1);
            {
                const short8 k0 = *(const short8*)&Kb[fi0];
                a0 = __builtin_amdgcn_mfma_f32_16x16x32_bf16(k0, qh, zero, 0, 0, 0);
                if (hasB1) {
                    const short8 k1 = *(const short8*)&Kb[fi1];
                    a1 = __builtin_amdgcn_mfma_f32_16x16x32_bf16(k1, qh, zero, 0, 0, 0);
                }
            }
            __builtin_amdgcn_s_setprio(0);

            if (ks == 10) {   // mask m >= 325 (tile 20: m = 320 + 4g + r)
                #pragma unroll
                for (int r = 0; r < 4; ++r)
                    a0[r] = (4 * g + r > 4) ? -1e30f : a0[r];
            }

            // |s| <= ~9 in log2 domain: no max subtraction needed
            a0[0] = exp2f(a0[0]); a0[1] = exp2f(a0[1]);
            a0[2] = exp2f(a0[2]); a0[3] = exp2f(a0[3]);
            ts0 += a0[0]; ts1 += a0[1]; ts2 += a0[2]; ts3 += a0[3];
            if (hasB1) {
                a1[0] = exp2f(a1[0]); a1[1] = exp2f(a1[1]);
                a1[2] = exp2f(a1[2]); a1[3] = exp2f(a1[3]);
                ts0 += a1[0]; ts1 += a1[1]; ts2 += a1[2]; ts3 += a1[3];
            }

            const short8 af = repack(a0, hasB1 ? a1 : a0, hasB1);
            const short8 v0 = *(const short8*)&Vt[( c        * PADV + ks * 32 + g * 8) ^ kswz];
            const short8 v1 = *(const short8*)&Vt[((c + 16)  * PADV + ks * 32 + g * 8) ^ kswz];
            __builtin_amdgcn_s_setprio(1);
            if (ks & 1) {
                o0b = __builtin_amdgcn_mfma_f32_16x16x32_bf16(af, v0, o0b, 0, 0, 0);
                o1b = __builtin_amdgcn_mfma_f32_16x16x32_bf16(af, v1, o1b, 0, 0, 0);
            } else {
                o0a = __builtin_amdgcn_mfma_f32_16x16x32_bf16(af, v0, o0a, 0, 0, 0);
                o1a = __builtin_amdgcn_mfma_f32_16x16x32_bf16(af, v1, o1a, 0, 0, 0);
            }
            __builtin_amdgcn_s_setprio(0);
        }

        float ts = (ts0 + ts1) + (ts2 + ts3);
        ts += __shfl_xor(ts, 16);
        ts += __shfl_xor(ts, 32);
        const float inv = 1.0f / ts;
        const f32x4 o0 = o0a + o0b;
        const f32x4 o1 = o1a + o1b;

        #pragma unroll
        for (int r = 0; r < 4; ++r) {
            const int row = qt * 16 + 4 * g + r;
            const float iv = __shfl(inv, 4 * g + r);
            if (row < NT) {
                op[(size_t)row * DKK + c]      = o0[r] * iv;
                op[(size_t)row * DKK + c + 16] = o1[r] * iv;
            }
        }
        qa = na; qb = nb;
    }
}

// ============================= FAT kernel ===================================
// var 1 only. r21: each slice split into TWO half-blocks (q-tiles 0-10 / 11-20)
// -> 768 blocks = exactly 3 per CU at 2-resident (perfect balance; was 384 =
// 1.5/CU -> makespan 2x block time). Inner loop byte-identical to r16/r20.
__global__ __launch_bounds__(512, 2)
void attn_fat(const float* __restrict__ Kf, const float* __restrict__ Vf,
              const float* __restrict__ Qs,
              const float* __restrict__ Kj, const float* __restrict__ Vfp,
              float* __restrict__ out)
{
    __shared__ __align__(16) unsigned short Kb[336 * DKK];   // bf16 hi (swizzled)
    __shared__ __align__(16) unsigned short Kl[336 * DKK];   // bf16 lo (swizzled)
    __shared__ __align__(16) unsigned short Vt[DKK * PADV];  // [d][m] bf16 (swizzled)

    const int tid  = threadIdx.x;
    const int bt   = blockIdx.x >> 1;
    const int half = blockIdx.x & 1;
    const int qlo  = half ? 11 : 0;
    const int qhi  = half ? NKT : 11;
    const size_t base = (size_t)bt * SLICE;

    const float* qp = Kf;
    const float* kp = Qs;
    const float* vp = Vf;
    float* op = out + (size_t)1 * TOTE + base;

    // ---- stage K -> Kb (hi) + Kl (lo), FlowSpeed applied ----
    for (int i8 = tid; i8 < SLICE / 8; i8 += 512) {
        const int idx = i8 * 8;
        const int m   = idx >> 5;
        const int sidx = swz(idx, m);
        const float* s = kp + base + idx;
        float4 a = *(const float4*)s;
        float4 b = *(const float4*)(s + 4);
        const float kj = Kj[m];
        const float rv = 1.0f / (Vfp[m] + 1e-5f);
        a.x = kj * (a.x - a.x * a.x * rv);
        a.y = kj * (a.y - a.y * a.y * rv);
        a.z = kj * (a.z - a.z * a.z * rv);
        a.w = kj * (a.w - a.w * a.w * rv);
        b.x = kj * (b.x - b.x * b.x * rv);
        b.y = kj * (b.y - b.y * b.y * rv);
        b.z = kj * (b.z - b.z * b.z * rv);
        b.w = kj * (b.w - b.w * b.w * rv);
        uint4 hw, lw;
        hw.x = pk2_split(a.x, a.y, lw.x);
        hw.y = pk2_split(a.z, a.w, lw.y);
        hw.z = pk2_split(b.x, b.y, lw.z);
        hw.w = pk2_split(b.z, b.w, lw.w);
        *(uint4*)&Kb[sidx] = hw;
        *(uint4*)&Kl[sidx] = lw;
    }

    // ---- stage V -> Vt (coalesced map) ----
    for (int gi = tid; gi < VGRAN; gi += 512) {
        const int dd = gi & 31;
        const int m8 = gi >> 5;
        const int mb = m8 * 8;
        float v[8];
        #pragma unroll
        for (int i = 0; i < 8; ++i) {
            const int m = mb + i;
            v[i] = (m < NT) ? vp[base + (size_t)m * DKK + dd] : 0.0f;
        }
        uint4 pkv;
        pkv.x = cvtpk(v[0], v[1]); pkv.y = cvtpk(v[2], v[3]);
        pkv.z = cvtpk(v[4], v[5]); pkv.w = cvtpk(v[6], v[7]);
        *(uint4*)&Vt[swz(dd * PADV + mb, dd)] = pkv;
    }
    __syncthreads();

    const int lane = tid & 63;
    const int wv   = tid >> 6;
    const int c    = lane & 15;
    const int g    = lane >> 4;
    const int kswz = (c & 7) << 3;
    const f32x4 zero = {0.f, 0.f, 0.f, 0.f};

    int qt = qlo + wv;
    float4 qa, qb;
    {   // preload first Q frag (qt <= 18 always -> row valid before clamp)
        int qr = qt * 16 + c; if (qr > NT - 1) qr = NT - 1;
        const float* s = qp + base + (size_t)qr * DKK + g * 8;
        qa = *(const float4*)s; qb = *(const float4*)(s + 4);
    }

    for (; qt < qhi; qt += 8) {
        float4 na, nb;
        const bool more = (qt + 8) < qhi;
        if (more) {
            int qr = (qt + 8) * 16 + c; if (qr > NT - 1) qr = NT - 1;
            const float* s = qp + base + (size_t)qr * DKK + g * 8;
            na = *(const float4*)s; nb = *(const float4*)(s + 4);
        }

        uint4 qwh, qwl;
        qwh.x = pk2_split(qa.x * SCALE2, qa.y * SCALE2, qwl.x);
        qwh.y = pk2_split(qa.z * SCALE2, qa.w * SCALE2, qwl.y);
        qwh.z = pk2_split(qb.x * SCALE2, qb.y * SCALE2, qwl.z);
        qwh.w = pk2_split(qb.z * SCALE2, qb.w * SCALE2, qwl.w);
        const short8 qh = __builtin_bit_cast(short8, qwh);
        const short8 ql = __builtin_bit_cast(short8, qwl);

        f32x4 o0a = zero, o1a = zero, o0b = zero, o1b = zero;
        float ts0 = 0.f, ts1 = 0.f, ts2 = 0.f, ts3 = 0.f;
        float mrow = -1e30f;

        #pragma unroll
        for (int ks = 0; ks < 11; ++ks) {
            const int fi0 = (((2 * ks) * 16 + c) * DKK + g * 8) ^ kswz;
            const int fi1 = fi0 + 16 * DKK;
            const bool hasB1 = (ks < 10);
            f32x4 a0, a1;

            __builtin_amdgcn_s_setprio(1);
            {
                const short8 kh = *(const short8*)&Kb[fi0];
                const short8 kl = *(const short8*)&Kl[fi0];
                f32x4 t = __builtin_amdgcn_mfma_f32_16x16x32_bf16(kh, ql, zero, 0, 0, 0);
                t = __builtin_amdgcn_mfma_f32_16x16x32_bf16(kl, qh, t, 0, 0, 0);
                a0 = __builtin_amdgcn_mfma_f32_16x16x32_bf16(kh, qh, t, 0, 0, 0);
            }
            if (hasB1) {
                const short8 kh = *(const short8*)&Kb[fi1];
                const short8 kl = *(const short8*)&Kl[fi1];
                f32x4 t = __builtin_amdgcn_mfma_f32_16x16x32_bf16(kh, ql, zero, 0, 0, 0);
                t = __builtin_amdgcn_mfma_f32_16x16x32_bf16(kl, qh, t, 0, 0, 0);
                a1 = __builtin_amdgcn_mfma_f32_16x16x32_bf16(kh, qh, t, 0, 0, 0);
            }
            __builtin_amdgcn_s_setprio(0);

            if (ks == 10) {
                #pragma unroll
                for (int r = 0; r < 4; ++r)
                    a0[r] = (4 * g + r > 4) ? -1e30f : a0[r];
            }

            float pm = fmaxf(fmaxf(a0[0], a0[1]), fmaxf(a0[2], a0[3]));
            if (hasB1)
                pm = fmaxf(pm, fmaxf(fmaxf(a1[0], a1[1]), fmaxf(a1[2], a1[3])));
            pm = fmaxf(pm, __shfl_xor(pm, 16));
            pm = fmaxf(pm, __shfl_xor(pm, 32));
            if (__any(pm > mrow)) {          // wave-uniform defer-skip
                const float mn = fmaxf(mrow, pm);
                const float f = exp2f(mrow - mn);   // 0 on first chunk
                mrow = mn;
                ts0 *= f; ts1 *= f; ts2 *= f; ts3 *= f;
                #pragma unroll
                for (int r = 0; r < 4; ++r) {
                    const float fr = __shfl(f, 4 * g + r);
                    o0a[r] *= fr; o1a[r] *= fr;
                    o0b[r] *= fr; o1b[r] *= fr;
                }
            }
            a0[0] = exp2f(a0[0] - mrow); a0[1] = exp2f(a0[1] - mrow);
            a0[2] = exp2f(a0[2] - mrow); a0[3] = exp2f(a0[3] - mrow);
            ts0 += a0[0]; ts1 += a0[1]; ts2 += a0[2]; ts3 += a0[3];
            if (hasB1) {
                a1[0] = exp2f(a1[0] - mrow); a1[1] = exp2f(a1[1] - mrow);
                a1[2] = exp2f(a1[2] - mrow); a1[3] = exp2f(a1[3] - mrow);
                ts0 += a1[0]; ts1 += a1[1]; ts2 += a1[2]; ts3 += a1[3];
            }

            const short8 af = repack(a0, hasB1 ? a1 : a0, hasB1);
            const short8 v0 = *(const short8*)&Vt[( c        * PADV + ks * 32 + g * 8) ^ kswz];
            const short8 v1 = *(const short8*)&Vt[((c + 16)  * PADV + ks * 32 + g * 8) ^ kswz];
            __builtin_amdgcn_s_setprio(1);
            if (ks & 1) {
                o0b = __builtin_amdgcn_mfma_f32_16x16x32_bf16(af, v0, o0b, 0, 0, 0);
                o1b = __builtin_amdgcn_mfma_f32_16x16x32_bf16(af, v1, o1b, 0, 0, 0);
            } else {
                o0a = __builtin_amdgcn_mfma_f32_16x16x32_bf16(af, v0, o0a, 0, 0, 0);
                o1a = __builtin_amdgcn_mfma_f32_16x16x32_bf16(af, v1, o1a, 0, 0, 0);
            }
            __builtin_amdgcn_s_setprio(0);
        }

        float ts = (ts0 + ts1) + (ts2 + ts3);
        ts += __shfl_xor(ts, 16);
        ts += __shfl_xor(ts, 32);
        const float inv = 1.0f / ts;
        const f32x4 o0 = o0a + o0b;
        const f32x4 o1 = o1a + o1b;

        #pragma unroll
        for (int r = 0; r < 4; ++r) {
            const int row = qt * 16 + 4 * g + r;
            const float iv = __shfl(inv, 4 * g + r);
            if (row < NT) {
                op[(size_t)row * DKK + c]      = o0[r] * iv;
                op[(size_t)row * DKK + c + 16] = o1[r] * iv;
            }
        }
        qa = na; qb = nb;
    }
}

extern "C" void kernel_launch(void* const* d_in, const int* in_sizes, int n_in,
                              void* d_out, int out_size, void* d_ws, size_t ws_size,
                              hipStream_t stream) {
    const float* Qf  = (const float*)d_in[0];
    const float* Kf  = (const float*)d_in[1];
    const float* Vf  = (const float*)d_in[2];
    const float* Qs  = (const float*)d_in[3];
    const float* Ks  = (const float*)d_in[4];
    const float* Vs  = (const float*)d_in[5];
    const float* Kj  = (const float*)d_in[6];
    const float* Vfp = (const float*)d_in[7];
    float* out = (float*)d_out;

    attn_slim<<<dim3(NSL * 3), dim3(512), 0, stream>>>(Qf, Kf, Vf, Qs, Ks, Vs, out);
    attn_fat <<<dim3(NSL * 2), dim3(512), 0, stream>>>(Kf, Vf, Qs, Kj, Vfp, out);
}